// Round 5
// baseline (900.694 us; speedup 1.0000x reference)
//
#include <hip/hip_runtime.h>

#define B_SZ 64
#define S_SZ 2048
#define RNN 1024
#define ATT 512
#define NCHUNK 64
#define CHUNK_S (S_SZ / NCHUNK)   // 32
#define KSPL 2                    // k-split halves for the h-GEMM

// ws layout in floats:
//   att_h_part: [KSPL][B][ATT]      off 0         (65536)
//   partials  : [B][NCHUNK][RNN]    off 65536     (4194304)
//   usum      : [B][NCHUNK]         off 4259840   (4096)
//   cnt       : [B] (int)           off 4263936   (64)
#define OFF_ATTHP  0
#define OFF_PART   65536
#define OFF_USUM   4259840
#define OFF_CNT    4263936

// tanh(x) = 1 - 2/(1 + 2^(x * 2/ln2))
__device__ __forceinline__ float fast_tanh(float x) {
    float t = __builtin_exp2f(x * 2.885390082f);
    return 1.0f - 2.0f * __builtin_amdgcn_rcpf(t + 1.0f);
}

// --- Kernel 0: att_h_part[ks][b][j] = h[b, ks*512..+512) . W_h[j, same) ---
// grid (4, KSPL, B), block 128; 4 independent accumulators (no serial FMA chain)
__global__ __launch_bounds__(128) void k_atth(const float* __restrict__ h,
                                              const float* __restrict__ Wh,
                                              float* __restrict__ att_h_part) {
    int b  = blockIdx.z;
    int ks = blockIdx.y;
    int j  = blockIdx.x * 128 + threadIdx.x;   // 0..511
    int kbase = ks * (RNN / KSPL);

    __shared__ float hs[RNN / KSPL];           // 512 floats
    for (int i = threadIdx.x; i < RNN / KSPL; i += 128)
        hs[i] = h[(size_t)b * RNN + kbase + i];
    __syncthreads();

    const float4* w4 = (const float4*)(Wh + (size_t)j * RNN + kbase);
    const float4* h4 = (const float4*)hs;
    float a0 = 0.f, a1 = 0.f, a2 = 0.f, a3 = 0.f;
    #pragma unroll 4
    for (int k = 0; k < (RNN / KSPL) / 4; k += 4) {
        float4 w, hv;
        w = w4[k + 0]; hv = h4[k + 0];
        a0 += w.x * hv.x + w.y * hv.y + w.z * hv.z + w.w * hv.w;
        w = w4[k + 1]; hv = h4[k + 1];
        a1 += w.x * hv.x + w.y * hv.y + w.z * hv.z + w.w * hv.w;
        w = w4[k + 2]; hv = h4[k + 2];
        a2 += w.x * hv.x + w.y * hv.y + w.z * hv.z + w.w * hv.w;
        w = w4[k + 3]; hv = h4[k + 3];
        a3 += w.x * hv.x + w.y * hv.y + w.z * hv.z + w.w * hv.w;
    }
    att_h_part[((size_t)ks * B_SZ + b) * ATT + j] = (a0 + a1) + (a2 + a3);
}

// --- Fused: per (chunk c, batch b):
//   compact active rows (ballot+rank); scores+exp for active rows only;
//   weighted gather-sum of att_feats active rows; last block per b reduces.
// grid (NCHUNK, B), block 256 = 4 waves
__global__ __launch_bounds__(256, 6) void k_fused(const float* __restrict__ p,
                                                  const float* __restrict__ att_h_part,
                                                  const float* __restrict__ bh,
                                                  const float* __restrict__ w_a,
                                                  const float* __restrict__ b_a,
                                                  const int* __restrict__ mask,
                                                  const float* __restrict__ feats,
                                                  float* __restrict__ partials,
                                                  float* __restrict__ usum,
                                                  int* __restrict__ cnt,
                                                  float* __restrict__ out) {
    int c = blockIdx.x;
    int b = blockIdx.y;
    int t = threadIdx.x;
    int s0 = c * CHUNK_S;

    __shared__ float ah[ATT];
    __shared__ float wa[ATT];
    __shared__ float u_c[64];          // padded to 64 (zeros beyond nact)
    __shared__ int   active[CHUNK_S];
    __shared__ int   nact_s;
    __shared__ int   last_s;

    const float* ph0 = att_h_part + (size_t)b * ATT;
    const float* ph1 = att_h_part + ((size_t)B_SZ + b) * ATT;
    for (int i = t; i < ATT; i += 256) {
        ah[i] = ph0[i] + ph1[i] + bh[i];
        wa[i] = w_a[i];
    }
    if (t < 64) u_c[t] = 0.f;
    if (t < CHUNK_S) {
        int m = mask[(size_t)b * S_SZ + s0 + t];
        unsigned long long bal = __ballot(m != 0);
        int rank = __popcll(bal & ((1ULL << (unsigned)t) - 1ULL));
        if (m) active[rank] = t;
        if (t == 0) nact_s = (int)__popcll(bal);
    }
    __syncthreads();
    int nact = nact_s;

    int wave = t >> 6;
    int lane = t & 63;
    float ba = b_a[0];

    const float4* ah4 = (const float4*)ah;
    const float4* wa4 = (const float4*)wa;
    float4 a0 = ah4[lane];
    float4 a1 = ah4[64 + lane];
    float4 w0 = wa4[lane];
    float4 w1 = wa4[64 + lane];

    // phase 1: active rows round-robin across 4 waves
    const float4* pbase = (const float4*)(p + ((size_t)b * S_SZ + s0) * ATT);
    for (int k = wave; k < nact; k += 4) {
        int sl = active[k];
        const float4* p4 = pbase + (size_t)sl * 128;
        float4 x0 = p4[lane];
        float4 x1 = p4[64 + lane];

        float part;
        part  = w0.x * fast_tanh(x0.x + a0.x);
        part += w0.y * fast_tanh(x0.y + a0.y);
        part += w0.z * fast_tanh(x0.z + a0.z);
        part += w0.w * fast_tanh(x0.w + a0.w);
        part += w1.x * fast_tanh(x1.x + a1.x);
        part += w1.y * fast_tanh(x1.y + a1.y);
        part += w1.z * fast_tanh(x1.z + a1.z);
        part += w1.w * fast_tanh(x1.w + a1.w);

        #pragma unroll
        for (int off = 32; off > 0; off >>= 1)
            part += __shfl_xor(part, off, 64);

        if (lane == 0) {
            float sc = fminf(part + ba, 80.f);
            u_c[k] = __builtin_expf(sc);
        }
    }
    __syncthreads();

    // phase 2: weighted gather-sum over active rows; thread t owns cols 4t..4t+3
    const float4* f4 = (const float4*)(feats + ((size_t)b * S_SZ + s0) * RNN);
    float4 acc = {0.f, 0.f, 0.f, 0.f};
    int k = 0;
    for (; k + 4 <= nact; k += 4) {
        int r0 = active[k + 0], r1 = active[k + 1];
        int r2 = active[k + 2], r3 = active[k + 3];
        float g0 = u_c[k + 0], g1 = u_c[k + 1];
        float g2 = u_c[k + 2], g3 = u_c[k + 3];
        float4 v0 = f4[(size_t)r0 * 256 + t];
        float4 v1 = f4[(size_t)r1 * 256 + t];
        float4 v2 = f4[(size_t)r2 * 256 + t];
        float4 v3 = f4[(size_t)r3 * 256 + t];
        acc.x += g0 * v0.x; acc.y += g0 * v0.y; acc.z += g0 * v0.z; acc.w += g0 * v0.w;
        acc.x += g1 * v1.x; acc.y += g1 * v1.y; acc.z += g1 * v1.z; acc.w += g1 * v1.w;
        acc.x += g2 * v2.x; acc.y += g2 * v2.y; acc.z += g2 * v2.z; acc.w += g2 * v2.w;
        acc.x += g3 * v3.x; acc.y += g3 * v3.y; acc.z += g3 * v3.z; acc.w += g3 * v3.w;
    }
    for (; k < nact; ++k) {
        int r = active[k];
        float g = u_c[k];
        float4 v = f4[(size_t)r * 256 + t];
        acc.x += g * v.x; acc.y += g * v.y; acc.z += g * v.z; acc.w += g * v.w;
    }
    ((float4*)partials)[((size_t)b * NCHUNK + c) * 256 + t] = acc;

    if (wave == 0) {
        float s = u_c[lane];   // zeros beyond nact
        #pragma unroll
        for (int off = 32; off > 0; off >>= 1)
            s += __shfl_xor(s, off, 64);
        if (lane == 0) usum[(size_t)b * NCHUNK + c] = s;
    }

    // last block per b reduces (fixed-order sum -> deterministic)
    __threadfence();
    if (t == 0) {
        int old = atomicAdd(&cnt[b], 1);
        last_s = (old == NCHUNK - 1);
    }
    __syncthreads();
    if (!last_s) return;
    __threadfence();

    float tot = 0.f;
    #pragma unroll 8
    for (int cc = 0; cc < NCHUNK; ++cc)
        tot += usum[(size_t)b * NCHUNK + cc];
    float inv = 1.f / tot;

    const float4* pr = (const float4*)partials + (size_t)b * NCHUNK * 256;
    float4 r = {0.f, 0.f, 0.f, 0.f};
    #pragma unroll 8
    for (int cc = 0; cc < NCHUNK; ++cc) {
        float4 v = pr[(size_t)cc * 256 + t];
        r.x += v.x; r.y += v.y; r.z += v.z; r.w += v.w;
    }
    r.x *= inv; r.y *= inv; r.z *= inv; r.w *= inv;
    ((float4*)out)[(size_t)b * 256 + t] = r;
}

extern "C" void kernel_launch(void* const* d_in, const int* in_sizes, int n_in,
                              void* d_out, int out_size, void* d_ws, size_t ws_size,
                              hipStream_t stream) {
    const float* h         = (const float*)d_in[0];
    const float* att_feats = (const float*)d_in[1];
    const float* p_att     = (const float*)d_in[2];
    const int*   att_masks = (const int*)d_in[3];
    const float* W_h       = (const float*)d_in[4];
    const float* b_h       = (const float*)d_in[5];
    const float* w_a       = (const float*)d_in[6];
    const float* b_a       = (const float*)d_in[7];
    float* out = (float*)d_out;

    float* wsf = (float*)d_ws;
    float* att_h_part = wsf + OFF_ATTHP;
    float* partials   = wsf + OFF_PART;
    float* usum       = wsf + OFF_USUM;
    int*   cnt        = (int*)(wsf + OFF_CNT);

    hipMemsetAsync(cnt, 0, B_SZ * sizeof(int), stream);
    k_atth<<<dim3(4, KSPL, B_SZ), 128, 0, stream>>>(h, W_h, att_h_part);
    k_fused<<<dim3(NCHUNK, B_SZ), 256, 0, stream>>>(p_att, att_h_part, b_h, w_a, b_a,
                                                    att_masks, att_feats,
                                                    partials, usum, cnt, out);
}

// Round 6
// 103.745 us; speedup vs baseline: 8.6818x; 8.6818x over previous
//
#include <hip/hip_runtime.h>

#define B_SZ 64
#define S_SZ 2048
#define RNN 1024
#define ATT 512
#define NCHUNK 32
#define CHUNK_S (S_SZ / NCHUNK)   // 64
#define KSPL 2                    // k-split halves for the h-GEMM

// ws layout in floats:
//   att_h_part: [KSPL][B][ATT]      off 0         (65536)
//   partials  : [B][NCHUNK][RNN]    off 65536     (2097152)
//   usum      : [B][NCHUNK]         off 2162688   (2048)
#define OFF_ATTHP  0
#define OFF_PART   65536
#define OFF_USUM   2162688

// tanh(x) = 1 - 2/(1 + 2^(x * 2/ln2))
__device__ __forceinline__ float fast_tanh(float x) {
    float t = __builtin_exp2f(x * 2.885390082f);
    return 1.0f - 2.0f * __builtin_amdgcn_rcpf(t + 1.0f);
}

// --- Kernel 0: att_h_part[ks][b][j] = h[b, ks*512..+512) . W_h[j, same) ---
// grid (4, KSPL, B), block 128; 4 independent accumulators
__global__ __launch_bounds__(128) void k_atth(const float* __restrict__ h,
                                              const float* __restrict__ Wh,
                                              float* __restrict__ att_h_part) {
    int b  = blockIdx.z;
    int ks = blockIdx.y;
    int j  = blockIdx.x * 128 + threadIdx.x;   // 0..511
    int kbase = ks * (RNN / KSPL);

    __shared__ float hs[RNN / KSPL];           // 512 floats
    for (int i = threadIdx.x; i < RNN / KSPL; i += 128)
        hs[i] = h[(size_t)b * RNN + kbase + i];
    __syncthreads();

    const float4* w4 = (const float4*)(Wh + (size_t)j * RNN + kbase);
    const float4* h4 = (const float4*)hs;
    float a0 = 0.f, a1 = 0.f, a2 = 0.f, a3 = 0.f;
    #pragma unroll 4
    for (int k = 0; k < (RNN / KSPL) / 4; k += 4) {
        float4 w, hv;
        w = w4[k + 0]; hv = h4[k + 0];
        a0 += w.x * hv.x + w.y * hv.y + w.z * hv.z + w.w * hv.w;
        w = w4[k + 1]; hv = h4[k + 1];
        a1 += w.x * hv.x + w.y * hv.y + w.z * hv.z + w.w * hv.w;
        w = w4[k + 2]; hv = h4[k + 2];
        a2 += w.x * hv.x + w.y * hv.y + w.z * hv.z + w.w * hv.w;
        w = w4[k + 3]; hv = h4[k + 3];
        a3 += w.x * hv.x + w.y * hv.y + w.z * hv.z + w.w * hv.w;
    }
    att_h_part[((size_t)ks * B_SZ + b) * ATT + j] = (a0 + a1) + (a2 + a3);
}

// --- Fused kernel with mask-compaction: per (chunk c, batch b):
//   build compact list of rows with mask!=0 (ballot + rank)
//   phase 1: u_c[k] = exp(w_a . tanh(p[b,row_k,:]+att_h[b,:]) + b_a)  (active rows only)
//   phase 2: partials[b,c,:] = sum_k u_c[k]*att_feats[b,row_k,:];  usum[b,c] = sum u_c
// grid (NCHUNK, B), block 256 = 4 waves
__global__ __launch_bounds__(256) void k_fused(const float* __restrict__ p,
                                               const float* __restrict__ att_h_part,
                                               const float* __restrict__ bh,
                                               const float* __restrict__ w_a,
                                               const float* __restrict__ b_a,
                                               const int* __restrict__ mask,
                                               const float* __restrict__ feats,
                                               float* __restrict__ partials,
                                               float* __restrict__ usum) {
    int c = blockIdx.x;
    int b = blockIdx.y;
    int t = threadIdx.x;
    int s0 = c * CHUNK_S;

    __shared__ float ah[ATT];
    __shared__ float wa[ATT];
    __shared__ float u_c[CHUNK_S];     // compacted unnormalized weights (zeros beyond nact)
    __shared__ int   active[CHUNK_S];  // compacted row indices (within chunk)
    __shared__ int   nact_s;

    const float* ph0 = att_h_part + (size_t)b * ATT;
    const float* ph1 = att_h_part + ((size_t)B_SZ + b) * ATT;
    for (int i = t; i < ATT; i += 256) {
        ah[i] = ph0[i] + ph1[i] + bh[i];
        wa[i] = w_a[i];
    }
    if (t < CHUNK_S) {
        u_c[t] = 0.f;
        int m = mask[(size_t)b * S_SZ + s0 + t];
        unsigned long long bal = __ballot(m != 0);
        int rank = __popcll(bal & ((1ULL << (unsigned)t) - 1ULL));
        if (m) active[rank] = t;
        if (t == 0) nact_s = (int)__popcll(bal);
    }
    __syncthreads();
    int nact = nact_s;

    int wave = t >> 6;
    int lane = t & 63;
    float ba = b_a[0];

    const float4* ah4 = (const float4*)ah;
    const float4* wa4 = (const float4*)wa;
    float4 a0 = ah4[lane];
    float4 a1 = ah4[64 + lane];
    float4 w0 = wa4[lane];
    float4 w1 = wa4[64 + lane];

    // phase 1: active rows round-robin across 4 waves
    const float4* pbase = (const float4*)(p + ((size_t)b * S_SZ + s0) * ATT);
    for (int k = wave; k < nact; k += 4) {
        int sl = active[k];
        const float4* p4 = pbase + (size_t)sl * 128;
        float4 x0 = p4[lane];
        float4 x1 = p4[64 + lane];

        float part;
        part  = w0.x * fast_tanh(x0.x + a0.x);
        part += w0.y * fast_tanh(x0.y + a0.y);
        part += w0.z * fast_tanh(x0.z + a0.z);
        part += w0.w * fast_tanh(x0.w + a0.w);
        part += w1.x * fast_tanh(x1.x + a1.x);
        part += w1.y * fast_tanh(x1.y + a1.y);
        part += w1.z * fast_tanh(x1.z + a1.z);
        part += w1.w * fast_tanh(x1.w + a1.w);

        #pragma unroll
        for (int off = 32; off > 0; off >>= 1)
            part += __shfl_xor(part, off, 64);

        if (lane == 0) {
            float sc = fminf(part + ba, 80.f);
            u_c[k] = __builtin_expf(sc);   // mask==1 for all active rows
        }
    }
    __syncthreads();

    // phase 2: weighted gather-sum over active rows; thread t owns cols 4t..4t+3
    const float4* f4 = (const float4*)(feats + ((size_t)b * S_SZ + s0) * RNN);
    float4 acc = {0.f, 0.f, 0.f, 0.f};
    int k = 0;
    for (; k + 4 <= nact; k += 4) {
        int r0 = active[k + 0], r1 = active[k + 1];
        int r2 = active[k + 2], r3 = active[k + 3];
        float g0 = u_c[k + 0], g1 = u_c[k + 1];
        float g2 = u_c[k + 2], g3 = u_c[k + 3];
        float4 v0 = f4[(size_t)r0 * 256 + t];
        float4 v1 = f4[(size_t)r1 * 256 + t];
        float4 v2 = f4[(size_t)r2 * 256 + t];
        float4 v3 = f4[(size_t)r3 * 256 + t];
        acc.x += g0 * v0.x; acc.y += g0 * v0.y; acc.z += g0 * v0.z; acc.w += g0 * v0.w;
        acc.x += g1 * v1.x; acc.y += g1 * v1.y; acc.z += g1 * v1.z; acc.w += g1 * v1.w;
        acc.x += g2 * v2.x; acc.y += g2 * v2.y; acc.z += g2 * v2.z; acc.w += g2 * v2.w;
        acc.x += g3 * v3.x; acc.y += g3 * v3.y; acc.z += g3 * v3.z; acc.w += g3 * v3.w;
    }
    for (; k < nact; ++k) {
        int r = active[k];
        float g = u_c[k];
        float4 v = f4[(size_t)r * 256 + t];
        acc.x += g * v.x; acc.y += g * v.y; acc.z += g * v.z; acc.w += g * v.w;
    }
    ((float4*)partials)[((size_t)b * NCHUNK + c) * 256 + t] = acc;

    if (wave == 0) {
        float s = u_c[lane];   // zeros beyond nact
        #pragma unroll
        for (int off = 32; off > 0; off >>= 1)
            s += __shfl_xor(s, off, 64);
        if (lane == 0) usum[(size_t)b * NCHUNK + c] = s;
    }
}

// --- Reduce: out[b,j] = (sum_c partials[b,c,j]) / (sum_c usum[b,c]) ---
// grid (RNN/256, B), block 256
__global__ __launch_bounds__(256) void k_reduce(const float* __restrict__ partials,
                                                const float* __restrict__ usum,
                                                float* __restrict__ out) {
    int b = blockIdx.y;
    int j = blockIdx.x * 256 + threadIdx.x;

    float tot = 0.f;
    #pragma unroll
    for (int c = 0; c < NCHUNK; ++c)
        tot += usum[(size_t)b * NCHUNK + c];   // block-uniform -> scalar loads

    float acc = 0.f;
    #pragma unroll 8
    for (int c = 0; c < NCHUNK; ++c)
        acc += partials[((size_t)b * NCHUNK + c) * RNN + j];

    out[(size_t)b * RNN + j] = acc / tot;
}

extern "C" void kernel_launch(void* const* d_in, const int* in_sizes, int n_in,
                              void* d_out, int out_size, void* d_ws, size_t ws_size,
                              hipStream_t stream) {
    const float* h         = (const float*)d_in[0];
    const float* att_feats = (const float*)d_in[1];
    const float* p_att     = (const float*)d_in[2];
    const int*   att_masks = (const int*)d_in[3];
    const float* W_h       = (const float*)d_in[4];
    const float* b_h       = (const float*)d_in[5];
    const float* w_a       = (const float*)d_in[6];
    const float* b_a       = (const float*)d_in[7];
    float* out = (float*)d_out;

    float* wsf = (float*)d_ws;
    float* att_h_part = wsf + OFF_ATTHP;
    float* partials   = wsf + OFF_PART;
    float* usum       = wsf + OFF_USUM;

    k_atth<<<dim3(4, KSPL, B_SZ), 128, 0, stream>>>(h, W_h, att_h_part);
    k_fused<<<dim3(NCHUNK, B_SZ), 256, 0, stream>>>(p_att, att_h_part, b_h, w_a, b_a,
                                                    att_masks, att_feats,
                                                    partials, usum);
    k_reduce<<<dim3(RNN / 256, B_SZ), 256, 0, stream>>>(partials, usum, out);
}